// Round 10
// baseline (130.969 us; speedup 1.0000x reference)
//
#include <hip/hip_runtime.h>
#include <hip/hip_bf16.h>
#include <cstdint>
#include <cstddef>

#define NV    8192   // nodes
#define KIN   512    // in features
#define MOUT  128    // out features
#define LOG2E 1.4426950408889634f

typedef __attribute__((ext_vector_type(4))) float f32x4;
typedef __attribute__((ext_vector_type(8))) short short8;

__device__ __forceinline__ float elu1(float x) { return x > 0.f ? x : expm1f(x); }

__device__ __forceinline__ unsigned int pkbf2(float a, float b) {
  union { __hip_bfloat162 h2; unsigned int u; } r;
  r.h2 = __float22bfloat162_rn(make_float2(a, b));
  return r.u;
}

// ---------------- kernel 1: wh1/wh2 (log2-scaled) + fragB (bf16, MFMA-fragment order) ----------------
// fragB[jt][cg][ks][lane][e] = bf16(wh[jt*64+ks*32+(lane>>4)*8+e][cg*16+(lane&15)])
__global__ __launch_bounds__(256) void k_wh(const float* __restrict__ h,
                                            const float* __restrict__ w,
                                            const float* __restrict__ a1,
                                            const float* __restrict__ a2,
                                            unsigned short* __restrict__ fragB,
                                            float* __restrict__ wh1,
                                            float* __restrict__ wh2) {
  __shared__ __align__(16) float hT[64][36];
  __shared__ __align__(16) float wT[64][128];
  const int t = threadIdx.x;
  const int row0 = blockIdx.x * 32;
  const int hr = t >> 3, hu = t & 7;
  const int wc = t >> 1, whalf = t & 1;
  const int cg = t & 31, rg = t >> 5;
  const int c0 = cg * 4, r0 = rg * 4;
  float acc[4][4] = {};

  for (int kt = 0; kt < 8; ++kt) {
    const int k0 = kt * 64;
    __syncthreads();
#pragma unroll
    for (int v = 0; v < 8; ++v)
      hT[hu + 8 * v][hr] = h[(size_t)(row0 + hr) * KIN + k0 + hu + 8 * v];
#pragma unroll
    for (int mv = 0; mv < 8; ++mv) {
      const float4 wv4 = *(const float4*)&w[(size_t)wc * KIN + k0 + whalf * 32 + mv * 4];
      wT[whalf * 32 + mv * 4 + 0][wc] = wv4.x;
      wT[whalf * 32 + mv * 4 + 1][wc] = wv4.y;
      wT[whalf * 32 + mv * 4 + 2][wc] = wv4.z;
      wT[whalf * 32 + mv * 4 + 3][wc] = wv4.w;
    }
    __syncthreads();
#pragma unroll 8
    for (int kk = 0; kk < 64; ++kk) {
      const float4 hv = *(const float4*)&hT[kk][r0];
      const float4 wv4 = *(const float4*)&wT[kk][c0];
      const float hvv[4] = {hv.x, hv.y, hv.z, hv.w};
      const float wvv[4] = {wv4.x, wv4.y, wv4.z, wv4.w};
#pragma unroll
      for (int i = 0; i < 4; ++i)
#pragma unroll
        for (int j = 0; j < 4; ++j)
          acc[i][j] = fmaf(hvv[i], wvv[j], acc[i][j]);
    }
  }

  // fragB store: rows rg*4+i -> (lg=rg>>1, e=(rg&1)*4+i); cols cg*4+j -> (cgf=cg>>2, l15=(cg&3)*4+j)
  {
    const size_t jt = (size_t)(row0 >> 6);
    const int ks = (row0 >> 5) & 1;
    const int lg = rg >> 1, ebase = (rg & 1) * 4;
    const int cgf = cg >> 2;
    const size_t fbase = (((jt * 8 + cgf) * 2 + ks) * 64 + lg * 16) * 8 + ebase;
#pragma unroll
    for (int j = 0; j < 4; ++j) {
      const int l15 = (cg & 3) * 4 + j;
      uint2 o;
      o.x = pkbf2(acc[0][j], acc[1][j]);
      o.y = pkbf2(acc[2][j], acc[3][j]);
      *(uint2*)&fragB[fbase + (size_t)l15 * 8] = o;
    }
  }

  const float4 a1v = *(const float4*)&a1[c0];
  const float4 a2v = *(const float4*)&a2[c0];
#pragma unroll
  for (int i = 0; i < 4; ++i) {
    float s1 = acc[i][0] * a1v.x + acc[i][1] * a1v.y + acc[i][2] * a1v.z + acc[i][3] * a1v.w;
    float s2 = acc[i][0] * a2v.x + acc[i][1] * a2v.y + acc[i][2] * a2v.z + acc[i][3] * a2v.w;
#pragma unroll
    for (int off = 16; off > 0; off >>= 1) {
      s1 += __shfl_down(s1, off, 32);
      s2 += __shfl_down(s2, off, 32);
    }
    if (cg == 0) {
      wh1[row0 + r0 + i] = s1 * LOG2E;
      wh2[row0 + r0 + i] = s2 * LOG2E;
    }
  }
}

// ---- pack-group helpers: group G (0..15) = chunk (G>>2), 4 rows (G&3)*4.. per wave.
// One wave-load covers 4 rows x 256 B (lane = row(l>>4) x 16 consecutive j per 4 loads).
__device__ __forceinline__ void issue_grp(const int* __restrict__ base, int G, int wv,
                                          int lane, int4 (&dst)[4]) {
  const int c = G >> 2, rb4 = (G & 3) * 4;
  const int r = wv * 16 + rb4 + (lane >> 4);
  const int* p = base + (size_t)r * NV + c * 256 + (lane & 15) * 16;
  dst[0] = *(const int4*)(p);
  dst[1] = *(const int4*)(p + 4);
  dst[2] = *(const int4*)(p + 8);
  dst[3] = *(const int4*)(p + 12);
}

__device__ __forceinline__ void write_grp(char* sm, int G, int wv, int lane,
                                          const int4 (&src)[4]) {
  const int c = G >> 2, rb4 = (G & 3) * 4;
  const int r = wv * 16 + rb4 + (lane >> 4);
  unsigned int us = 0;
#pragma unroll
  for (int m = 0; m < 4; ++m) {
    us |= (unsigned)(src[m].x & 1) << (4 * m);
    us |= (unsigned)(src[m].y & 1) << (4 * m + 1);
    us |= (unsigned)(src[m].z & 1) << (4 * m + 2);
    us |= (unsigned)(src[m].w & 1) << (4 * m + 3);
  }
  const int l15q = lane & 15;
  const int tile = c * 4 + (l15q >> 2), slot = l15q & 3;
  *(unsigned short*)&sm[r * 136 + tile * 8 + slot * 2] = (unsigned short)us;
}

// ---------------- kernel 2: chunk-pipelined adj-pack + attention partials ----------------
// grid (128, 8) x 256. 64-row blocks, 16 tiles in 4 chunks of 4. Pack of chunk q+1 is
// interleaved with compute of chunk q (issue at tile T, LDS-write at T+2) so the 268 MB
// adj HBM stream hides under the VALU-bound P-compute. Only chunk 0 (~67 MB chip-wide)
// is exposed serially. __syncthreads only at chunk boundaries.
__global__ __launch_bounds__(256) void k_attn_p(const unsigned short* __restrict__ fragB,
                                                const int* __restrict__ adj,
                                                const float* __restrict__ wh1l,
                                                const float* __restrict__ wh2l,
                                                float* __restrict__ out_p,
                                                float* __restrict__ psum_p) {
  __shared__ char smask[64 * 136];   // uint2 mask per (row, tile): bit b of tile -> j=tile*64+b
  const int t = threadIdx.x;
  const int i0 = blockIdx.x * 64;
  const int jbase = blockIdx.y * 1024;
  const int lane = t & 63, wv = t >> 6;
  const int ih = wv & 1, ch = wv >> 1;
  const int l15 = lane & 15, lg = lane >> 4;

  const int* abase = adj + (size_t)i0 * NV + jbase;

  // ---- prologue: pack chunk 0; leave G4,G5 in flight ----
  int4 ga[4], gb[4];
  issue_grp(abase, 0, wv, lane, ga);
  issue_grp(abase, 1, wv, lane, gb);
  write_grp(smask, 0, wv, lane, ga);
  issue_grp(abase, 2, wv, lane, ga);
  write_grp(smask, 1, wv, lane, gb);
  issue_grp(abase, 3, wv, lane, gb);
  write_grp(smask, 2, wv, lane, ga);
  issue_grp(abase, 4, wv, lane, ga);
  write_grp(smask, 3, wv, lane, gb);
  issue_grp(abase, 5, wv, lane, gb);

  // ---- phase-1 setup ----
  const int rb = ih * 32;
  const float wh1a = wh1l[i0 + rb + l15];
  const float wh1b = wh1l[i0 + rb + 16 + l15];
  const char* mrowa = smask + (rb + l15) * 136;
  const char* mrowb = smask + (rb + 16 + l15) * 136;
  const unsigned short* bbase = fragB + (size_t)(jbase >> 6) * 8192 + ch * 4096 + lane * 8;
  const float* w2base = wh2l + jbase + lg * 8;

  f32x4 acc[2][4] = {};
  f32x4 accs[2] = {};
  short8 onesf;
#pragma unroll
  for (int e = 0; e < 8; ++e) onesf[e] = (short)0x3F80;  // bf16 1.0

  for (int q = 0; q < 4; ++q) {
    __syncthreads();   // chunk q's masks visible
#pragma unroll
    for (int tt = 0; tt < 4; ++tt) {
      const int T = q * 4 + tt;
      // pipeline: write masks of group T+4 (loaded at T-2), issue group T+6
      if (T + 4 < 16) {
        if ((tt & 1) == 0) {
          write_grp(smask, T + 4, wv, lane, ga);
          if (T + 6 < 16) issue_grp(abase, T + 6, wv, lane, ga);
        } else {
          write_grp(smask, T + 4, wv, lane, gb);
          if (T + 6 < 16) issue_grp(abase, T + 6, wv, lane, gb);
        }
      }
      // B fragments for tile T (issued early; latency hides under exp chain)
      short8 bf[8];
      {
        const unsigned short* bp = bbase + (size_t)T * 8192;
#pragma unroll
        for (int ks = 0; ks < 2; ++ks)
#pragma unroll
          for (int cgl = 0; cgl < 4; ++cgl)
            bf[ks * 4 + cgl] = *(const short8*)(bp + cgl * 1024 + ks * 512);
      }
      // masks + wh2 for tile T
      const uint2 m2a = *(const uint2*)&mrowa[T * 8];
      const uint2 m2b = *(const uint2*)&mrowb[T * 8];
      const float* w2p = w2base + T * 64;
      const float4 wq0 = *(const float4*)(w2p);
      const float4 wq1 = *(const float4*)(w2p + 4);
      const float4 wq2 = *(const float4*)(w2p + 32);
      const float4 wq3 = *(const float4*)(w2p + 36);
      const unsigned int m16a = ((m2a.x >> (8 * lg)) & 0xFFu) |
                                (((m2a.y >> (8 * lg)) & 0xFFu) << 8);
      const unsigned int m16b = ((m2b.x >> (8 * lg)) & 0xFFu) |
                                (((m2b.y >> (8 * lg)) & 0xFFu) << 8);

      short8 afa[2], afb[2];
#pragma unroll
      for (int ks = 0; ks < 2; ++ks) {
        const float4 wa = ks ? wq2 : wq0;
        const float4 wb = ks ? wq3 : wq1;
        const float w2v[8] = {wa.x, wa.y, wa.z, wa.w, wb.x, wb.y, wb.z, wb.w};
        union { short8 s8; unsigned int u[4]; } pka, pkb;
#pragma unroll
        for (int e = 0; e < 4; ++e) {
          const float x0 = wh1a + w2v[2 * e];
          const float x1 = wh1a + w2v[2 * e + 1];
          const float y0 = wh1b + w2v[2 * e];
          const float y1 = wh1b + w2v[2 * e + 1];
          const float lx0 = fmaxf(x0, 0.01f * x0);
          const float lx1 = fmaxf(x1, 0.01f * x1);
          const float ly0 = fmaxf(y0, 0.01f * y0);
          const float ly1 = fmaxf(y1, 0.01f * y1);
          float px0 = __builtin_amdgcn_exp2f(lx0);
          float px1 = __builtin_amdgcn_exp2f(lx1);
          float py0 = __builtin_amdgcn_exp2f(ly0);
          float py1 = __builtin_amdgcn_exp2f(ly1);
          px0 = ((m16a >> (ks * 8 + 2 * e)) & 1u) ? px0 : 0.f;
          px1 = ((m16a >> (ks * 8 + 2 * e + 1)) & 1u) ? px1 : 0.f;
          py0 = ((m16b >> (ks * 8 + 2 * e)) & 1u) ? py0 : 0.f;
          py1 = ((m16b >> (ks * 8 + 2 * e + 1)) & 1u) ? py1 : 0.f;
          pka.u[e] = pkbf2(px0, px1);
          pkb.u[e] = pkbf2(py0, py1);
        }
        afa[ks] = pka.s8;
        afb[ks] = pkb.s8;
      }
#pragma unroll
      for (int ks = 0; ks < 2; ++ks) {
        acc[0][0] = __builtin_amdgcn_mfma_f32_16x16x32_bf16(afa[ks], bf[ks * 4 + 0], acc[0][0], 0, 0, 0);
        acc[0][1] = __builtin_amdgcn_mfma_f32_16x16x32_bf16(afa[ks], bf[ks * 4 + 1], acc[0][1], 0, 0, 0);
        acc[0][2] = __builtin_amdgcn_mfma_f32_16x16x32_bf16(afa[ks], bf[ks * 4 + 2], acc[0][2], 0, 0, 0);
        acc[0][3] = __builtin_amdgcn_mfma_f32_16x16x32_bf16(afa[ks], bf[ks * 4 + 3], acc[0][3], 0, 0, 0);
        accs[0]   = __builtin_amdgcn_mfma_f32_16x16x32_bf16(afa[ks], onesf, accs[0], 0, 0, 0);
        acc[1][0] = __builtin_amdgcn_mfma_f32_16x16x32_bf16(afb[ks], bf[ks * 4 + 0], acc[1][0], 0, 0, 0);
        acc[1][1] = __builtin_amdgcn_mfma_f32_16x16x32_bf16(afb[ks], bf[ks * 4 + 1], acc[1][1], 0, 0, 0);
        acc[1][2] = __builtin_amdgcn_mfma_f32_16x16x32_bf16(afb[ks], bf[ks * 4 + 2], acc[1][2], 0, 0, 0);
        acc[1][3] = __builtin_amdgcn_mfma_f32_16x16x32_bf16(afb[ks], bf[ks * 4 + 3], acc[1][3], 0, 0, 0);
        accs[1]   = __builtin_amdgcn_mfma_f32_16x16x32_bf16(afb[ks], onesf, accs[1], 0, 0, 0);
      }
    }
  }

  // psum via ones-column: lane(l15=0,lg) reg r holds rowsum[rg*16 + lg*4 + r]
  if (ch == 0 && l15 == 0) {
#pragma unroll
    for (int rg = 0; rg < 2; ++rg)
#pragma unroll
      for (int r = 0; r < 4; ++r)
        psum_p[(size_t)blockIdx.y * NV + i0 + rb + rg * 16 + lg * 4 + r] = accs[rg][r];
  }

  // unnormalized partial tiles (C/D: col=l15, row=lg*4+r)
#pragma unroll
  for (int rg = 0; rg < 2; ++rg) {
    const size_t ob = ((size_t)blockIdx.y * NV + i0 + rb + rg * 16) * MOUT + ch * 64;
#pragma unroll
    for (int cgl = 0; cgl < 4; ++cgl)
#pragma unroll
      for (int r = 0; r < 4; ++r)
        out_p[ob + (size_t)(lg * 4 + r) * MOUT + cgl * 16 + l15] = acc[rg][cgl][r];
  }
}

// ---------------- kernel 3: combine partials, normalize, ELU ----------------
__global__ __launch_bounds__(256) void k_comb(const float* __restrict__ out_p,
                                              const float* __restrict__ psum_p,
                                              float* __restrict__ out, int S) {
  const int idx = (blockIdx.x * 256 + threadIdx.x) * 4;
  const int n = idx >> 7;  // MOUT = 128
  float denom = 0.f;
  for (int s = 0; s < S; ++s) denom += psum_p[(size_t)s * NV + n];
  float4 acc = {0.f, 0.f, 0.f, 0.f};
  for (int s = 0; s < S; ++s) {
    const float4 v = *(const float4*)&out_p[(size_t)s * NV * MOUT + idx];
    acc.x += v.x; acc.y += v.y; acc.z += v.z; acc.w += v.w;
  }
  const float inv = 1.f / denom;
  float4 o;
  o.x = elu1(acc.x * inv);
  o.y = elu1(acc.y * inv);
  o.z = elu1(acc.z * inv);
  o.w = elu1(acc.w * inv);
  *(float4*)&out[idx] = o;
}

extern "C" void kernel_launch(void* const* d_in, const int* in_sizes, int n_in,
                              void* d_out, int out_size, void* d_ws, size_t ws_size,
                              hipStream_t stream) {
  const float* h  = (const float*)d_in[0];
  const int* adj  = (const int*)d_in[1];
  const float* w  = (const float*)d_in[2];
  const float* a1 = (const float*)d_in[3];
  const float* a2 = (const float*)d_in[4];
  float* out = (float*)d_out;

  char* ws = (char*)d_ws;
  // layout: [fragB 2MB][wh1 32KB][wh2 32KB][psum_p 256KB][out_p 8*4MB]
  unsigned short* fragB = (unsigned short*)ws;
  size_t off = (size_t)MOUT * NV * 2;
  float* wh1 = (float*)(ws + off); off += (size_t)NV * 4;
  float* wh2 = (float*)(ws + off); off += (size_t)NV * 4;
  float* psum_p = (float*)(ws + off); off += (size_t)8 * NV * 4;
  float* out_p = (float*)(ws + off);

  k_wh<<<NV / 32, 256, 0, stream>>>(h, w, a1, a2, fragB, wh1, wh2);
  k_attn_p<<<dim3(NV / 64, 8), 256, 0, stream>>>(fragB, adj, wh1, wh2, out_p, psum_p);
  k_comb<<<(NV * MOUT / 4) / 256, 256, 0, stream>>>(out_p, psum_p, out, 8);
}